// Round 5
// baseline (277.041 us; speedup 1.0000x reference)
//
#include <hip/hip_runtime.h>
#include <hip/hip_bf16.h>
#include <hip/hip_fp16.h>

typedef unsigned short u16;
typedef __attribute__((ext_vector_type(8))) short short8;
typedef __attribute__((ext_vector_type(4))) short s16x4;
typedef __attribute__((ext_vector_type(8))) u16 u16x8;
typedef __attribute__((ext_vector_type(4))) u16 u16x4;
typedef __attribute__((ext_vector_type(2))) u16 u16x2;
typedef __attribute__((ext_vector_type(8))) _Float16 half8;
typedef __attribute__((ext_vector_type(4))) _Float16 half4;
typedef __attribute__((ext_vector_type(4))) float f32x4;
typedef __attribute__((ext_vector_type(2))) float f32x2;

#define NB 8
#define TQn 1024
#define TKn 4096
#define DINn 1024
#define DOUTn 256
#define NROWS (NB * TQn)
#define NKB (TKn / 128)
#define EXPSHIFT 40.0f
#define LP 36  // LDS row stride in u16 (72 B): l*18 % 32 distinct for 16 lanes

#define DEV static __device__ __forceinline__

DEV u16 f2bf(float x) {
    __hip_bfloat16 h = __float2bfloat16(x);
    return *reinterpret_cast<u16*>(&h);
}
DEV float bf2f(u16 u) {
    __hip_bfloat16 h;
    *reinterpret_cast<u16*>(&h) = u;
    return __bfloat162float(h);
}
DEV void split2(float x, u16& hi, u16& lo) {
    u16 h = f2bf(x);
    float hf = bf2f(h);
    hi = h;
    lo = f2bf(x - hf);
}
DEV void split4(const float4 v, u16x4& h, u16x4& l) {
    u16 h0, l0, h1, l1, h2, l2, h3, l3;
    split2(v.x, h0, l0);
    split2(v.y, h1, l1);
    split2(v.z, h2, l2);
    split2(v.w, h3, l3);
    h = (u16x4){h0, h1, h2, h3};
    l = (u16x4){l0, l1, l2, l3};
}
DEV short8 ld8s(const u16* p) {
    s16x4 a = *reinterpret_cast<const s16x4*>(p);
    s16x4 b = *reinterpret_cast<const s16x4*>(p + 4);
    short8 r;
    r[0] = a[0]; r[1] = a[1]; r[2] = a[2]; r[3] = a[3];
    r[4] = b[0]; r[5] = b[1]; r[6] = b[2]; r[7] = b[3];
    return r;
}
DEV half8 ld8h(const u16* p) {
    half4 a = *reinterpret_cast<const half4*>(p);
    half4 b = *reinterpret_cast<const half4*>(p + 4);
    half8 r;
    r[0] = a[0]; r[1] = a[1]; r[2] = a[2]; r[3] = a[3];
    r[4] = b[0]; r[5] = b[1]; r[6] = b[2]; r[7] = b[3];
    return r;
}
DEV void st8(u16* p, u16x8 v) {
    *reinterpret_cast<u16x4*>(p) = (u16x4){v[0], v[1], v[2], v[3]};
    *reinterpret_cast<u16x4*>(p + 4) = (u16x4){v[4], v[5], v[6], v[7]};
}

// ---------------------------------------------------------------------------
// Kernel 1: transpose+convert emb [B][TK][DOUT] fp32 -> embT [B][DOUT][TK] fp16
// ---------------------------------------------------------------------------
__global__ __launch_bounds__(256) void k_embT(const float* __restrict__ emb,
                                              _Float16* __restrict__ embT) {
    __shared__ float tile[64][65];
    const int b = blockIdx.z;
    const int k0 = blockIdx.x * 64;
    const int o0 = blockIdx.y * 64;
    const int t = threadIdx.x;
    const int c = t & 63;
    const int r0 = t >> 6;
#pragma unroll
    for (int i = 0; i < 16; i++) {
        int r = r0 + i * 4;
        tile[c][r] = emb[((size_t)b * TKn + k0 + r) * DOUTn + o0 + c];
    }
    __syncthreads();
#pragma unroll
    for (int i = 0; i < 16; i++) {
        int r = r0 + i * 4;
        embT[((size_t)b * DOUTn + o0 + r) * TKn + k0 + c] = (_Float16)tile[r][c];
    }
}

// ---------------------------------------------------------------------------
// Kernel 2: linear  decsmall = dec @ W^T + b, split into hi/lo bf16
// BM=128, BN=64, BK=32, 256 threads (4 waves, 2x2)
// ---------------------------------------------------------------------------
__global__ __launch_bounds__(256) void k_linear(const float* __restrict__ dec,
                                                const float* __restrict__ W,
                                                const float* __restrict__ bias,
                                                u16* __restrict__ ds_hi,
                                                u16* __restrict__ ds_lo) {
    __shared__ u16 sAh[128][LP], sAl[128][LP], sBh[64][LP], sBl[64][LP];
    const int t = threadIdx.x;
    const int m0 = blockIdx.x * 128;
    const int n0 = blockIdx.y * 64;
    const int w = t >> 6, lane = t & 63;
    const int wr = w >> 1, wc = w & 1;
    const int lr = lane & 15, g = lane >> 4, kg8 = g * 8;

    f32x4 acc[4][2];
#pragma unroll
    for (int m = 0; m < 4; m++)
#pragma unroll
        for (int n = 0; n < 2; n++) acc[m][n] = (f32x4){0.f, 0.f, 0.f, 0.f};

    for (int k0 = 0; k0 < DINn; k0 += 32) {
        __syncthreads();
#pragma unroll
        for (int i = 0; i < 4; i++) {
            int f = i * 256 + t;
            int row = f >> 3, c4 = (f & 7) * 4;
            const float4 v = *reinterpret_cast<const float4*>(
                dec + (size_t)(m0 + row) * DINn + k0 + c4);
            u16x4 h, l;
            split4(v, h, l);
            *reinterpret_cast<u16x4*>(&sAh[row][c4]) = h;
            *reinterpret_cast<u16x4*>(&sAl[row][c4]) = l;
        }
#pragma unroll
        for (int i = 0; i < 2; i++) {
            int f = i * 256 + t;
            int row = f >> 3, c4 = (f & 7) * 4;
            const float4 v = *reinterpret_cast<const float4*>(
                W + (size_t)(n0 + row) * DINn + k0 + c4);
            u16x4 h, l;
            split4(v, h, l);
            *reinterpret_cast<u16x4*>(&sBh[row][c4]) = h;
            *reinterpret_cast<u16x4*>(&sBl[row][c4]) = l;
        }
        __syncthreads();
        short8 ah[4], al[4], bh[2], bl[2];
#pragma unroll
        for (int m = 0; m < 4; m++) {
            int row = wr * 64 + m * 16 + lr;
            ah[m] = ld8s(&sAh[row][kg8]);
            al[m] = ld8s(&sAl[row][kg8]);
        }
#pragma unroll
        for (int n = 0; n < 2; n++) {
            int row = wc * 32 + n * 16 + lr;
            bh[n] = ld8s(&sBh[row][kg8]);
            bl[n] = ld8s(&sBl[row][kg8]);
        }
#pragma unroll
        for (int m = 0; m < 4; m++)
#pragma unroll
            for (int n = 0; n < 2; n++) {
                acc[m][n] = __builtin_amdgcn_mfma_f32_16x16x32_bf16(ah[m], bh[n], acc[m][n], 0, 0, 0);
                acc[m][n] = __builtin_amdgcn_mfma_f32_16x16x32_bf16(ah[m], bl[n], acc[m][n], 0, 0, 0);
                acc[m][n] = __builtin_amdgcn_mfma_f32_16x16x32_bf16(al[m], bh[n], acc[m][n], 0, 0, 0);
            }
    }
#pragma unroll
    for (int m = 0; m < 4; m++) {
#pragma unroll
        for (int n = 0; n < 2; n++) {
            int colg = n0 + wc * 32 + n * 16 + lr;
            float bv = bias[colg];
#pragma unroll
            for (int r = 0; r < 4; r++) {
                int rowg = m0 + wr * 64 + m * 16 + g * 4 + r;
                float v = acc[m][n][r] + bv;
                u16 h, l;
                split2(v, h, l);
                ds_hi[(size_t)rowg * DOUTn + colg] = h;
                ds_lo[(size_t)rowg * DOUTn + colg] = l;
            }
        }
    }
}

// ---------------------------------------------------------------------------
// Kernel 3: scores GEMM (split 3-MFMA) + mask + p_u = exp(s - 40) nt-write
//           + per-row partial sums -> partsum[kb][row]
// BM=128, BN=128, BK=32; XCD-aware decode: flat%8 = batch
// ---------------------------------------------------------------------------
__global__ __launch_bounds__(256) void k_scores_exp(const u16* __restrict__ ds_hi,
                                                    const u16* __restrict__ ds_lo,
                                                    const float* __restrict__ emb,
                                                    const int* __restrict__ emask,
                                                    float* __restrict__ attn,
                                                    float* __restrict__ partsum) {
    __shared__ u16 sAh[128][LP], sAl[128][LP], sBh[128][LP], sBl[128][LP];
    __shared__ float sSum[2][128];
    const int t = threadIdx.x;
    const int flat = blockIdx.x + 8 * (blockIdx.y + 32 * blockIdx.z);
    const int b = flat & 7;
    const int rest = flat >> 3;
    const int kb = rest & 31;
    const int q0 = (rest >> 5) * 128;
    const int kb0 = kb * 128;
    const int w = t >> 6, lane = t & 63;
    const int wr = w >> 1, wc = w & 1;
    const int lr = lane & 15, g = lane >> 4, kg8 = g * 8;

    f32x4 acc[4][4];
#pragma unroll
    for (int m = 0; m < 4; m++)
#pragma unroll
        for (int n = 0; n < 4; n++) acc[m][n] = (f32x4){0.f, 0.f, 0.f, 0.f};

    for (int o0 = 0; o0 < DOUTn; o0 += 32) {
        __syncthreads();
        // stage A: decsmall hi/lo bf16 128x32
#pragma unroll
        for (int i = 0; i < 2; i++) {
            int f8 = i * 256 + t;
            int row = f8 >> 2, c8 = (f8 & 3) * 8;
            size_t src = (size_t)(b * TQn + q0 + row) * DOUTn + o0 + c8;
            st8(&sAh[row][c8], *reinterpret_cast<const u16x8*>(ds_hi + src));
            st8(&sAl[row][c8], *reinterpret_cast<const u16x8*>(ds_lo + src));
        }
        // stage B: emb fp32 128x32 -> hi/lo
#pragma unroll
        for (int i = 0; i < 4; i++) {
            int f = i * 256 + t;
            int row = f >> 3, c4 = (f & 7) * 4;
            const float4 v = *reinterpret_cast<const float4*>(
                emb + (size_t)(b * TKn + kb0 + row) * DOUTn + o0 + c4);
            u16x4 h, l;
            split4(v, h, l);
            *reinterpret_cast<u16x4*>(&sBh[row][c4]) = h;
            *reinterpret_cast<u16x4*>(&sBl[row][c4]) = l;
        }
        __syncthreads();
        short8 ah[4], al[4], bh[4], bl[4];
#pragma unroll
        for (int m = 0; m < 4; m++) {
            int row = wr * 64 + m * 16 + lr;
            ah[m] = ld8s(&sAh[row][kg8]);
            al[m] = ld8s(&sAl[row][kg8]);
        }
#pragma unroll
        for (int n = 0; n < 4; n++) {
            int row = wc * 64 + n * 16 + lr;
            bh[n] = ld8s(&sBh[row][kg8]);
            bl[n] = ld8s(&sBl[row][kg8]);
        }
#pragma unroll
        for (int m = 0; m < 4; m++)
#pragma unroll
            for (int n = 0; n < 4; n++) {
                acc[m][n] = __builtin_amdgcn_mfma_f32_16x16x32_bf16(ah[m], bh[n], acc[m][n], 0, 0, 0);
                acc[m][n] = __builtin_amdgcn_mfma_f32_16x16x32_bf16(ah[m], bl[n], acc[m][n], 0, 0, 0);
                acc[m][n] = __builtin_amdgcn_mfma_f32_16x16x32_bf16(al[m], bh[n], acc[m][n], 0, 0, 0);
            }
    }
    // epilogue: mask + exp(s-40) + nt-write p_u + per-row sums
    const int* em = emask + (size_t)b * TKn;
    float* pout = attn + ((size_t)(b * TQn + q0)) * TKn + kb0;
    float rowAcc[4][4];
#pragma unroll
    for (int m = 0; m < 4; m++)
#pragma unroll
        for (int r = 0; r < 4; r++) rowAcc[m][r] = 0.f;

#pragma unroll
    for (int n = 0; n < 4; n++) {
        int colL = wc * 64 + n * 16 + lr;
        int mk = em[kb0 + colL];
#pragma unroll
        for (int m = 0; m < 4; m++) {
#pragma unroll
            for (int r = 0; r < 4; r++) {
                int rowL = wr * 64 + m * 16 + g * 4 + r;
                float p = mk ? __expf(acc[m][n][r] - EXPSHIFT) : 0.f;
                __builtin_nontemporal_store(p, &pout[(size_t)rowL * TKn + colL]);
                rowAcc[m][r] += p;
            }
        }
    }
#pragma unroll
    for (int m = 0; m < 4; m++) {
#pragma unroll
        for (int r = 0; r < 4; r++) {
            float v = rowAcc[m][r];
            v += __shfl_xor(v, 1);
            v += __shfl_xor(v, 2);
            v += __shfl_xor(v, 4);
            v += __shfl_xor(v, 8);
            if (lr == 0) sSum[wc][wr * 64 + m * 16 + g * 4 + r] = v;
        }
    }
    __syncthreads();
    if (t < 128) {
        partsum[(size_t)kb * NROWS + (size_t)b * TQn + q0 + t] =
            sSum[0][t] + sSum[1][t];
    }
}

// ---------------------------------------------------------------------------
// Kernel 4: inv_sum[row] = 1 / sum_kb partsum[kb][row]
// ---------------------------------------------------------------------------
__global__ __launch_bounds__(256) void k_rowsum(const float* __restrict__ partsum,
                                                float* __restrict__ inv_sum) {
    int row = blockIdx.x * 256 + threadIdx.x;
    float s = 0.f;
#pragma unroll
    for (int kb = 0; kb < NKB; kb++) s += partsum[(size_t)kb * NROWS + row];
    inv_sum[row] = 1.0f / s;
}

// ---------------------------------------------------------------------------
// Kernel 5: PV GEMM, full K=4096 per block (no split-K, no partials).
// Block: 32 q-rows x 256 o; 512 threads (8 waves: row-half x o-quarter).
// Reads p_u, scales by inv (final attn nt-write-back), fp16 MFMA vs embT,
// writes out directly. XCD-aware decode: flat%8 = batch.
// ---------------------------------------------------------------------------
__global__ __launch_bounds__(512) void k_pv3(float* __restrict__ attn,
                                             const _Float16* __restrict__ embT,
                                             const float* __restrict__ inv_sum,
                                             float* __restrict__ out) {
    __shared__ u16 sA[32][LP];
    __shared__ u16 sB[256][LP];
    const int t = threadIdx.x;
    const int flat = blockIdx.x + 32 * blockIdx.y;  // 0..255
    const int b = flat & 7;
    const int q0 = (flat >> 3) * 32;
    const int w = t >> 6, lane = t & 63;
    const int lr = lane & 15, g = lane >> 4, kg8 = g * 8;
    const int rh = w >> 2;       // row-half (0/1)
    const int oq = w & 3;        // o-quarter (0..3)
    const u16* ebt = reinterpret_cast<const u16*>(embT);

    // A-staging assignment: 16 threads per row, float2 each
    const int arow = t >> 4, c2 = (t & 15) * 2;
    const float inv = inv_sum[(size_t)b * TQn + q0 + arow];
    float* pA = attn + ((size_t)(b * TQn + q0 + arow)) * TKn + c2;

    f32x4 acc[4];
#pragma unroll
    for (int n = 0; n < 4; n++) acc[n] = (f32x4){0.f, 0.f, 0.f, 0.f};

    for (int ks = 0; ks < TKn; ks += 32) {
        __syncthreads();
        // stage A: p_u 32x32 fp32, scale by inv, nt-write final attn, cvt fp16
        {
            f32x2 v = *reinterpret_cast<const f32x2*>(pA + ks);
            v = v * inv;
            __builtin_nontemporal_store(v, reinterpret_cast<f32x2*>(pA + ks));
            u16x2 hv;
            hv[0] = __builtin_bit_cast(u16, (_Float16)v[0]);
            hv[1] = __builtin_bit_cast(u16, (_Float16)v[1]);
            *reinterpret_cast<u16x2*>(&sA[arow][c2]) = hv;
        }
        // stage B: embT 256 o x 32 k fp16
#pragma unroll
        for (int i = 0; i < 2; i++) {
            int f = i * 512 + t;
            int brow = f >> 2, bc8 = (f & 3) * 8;
            st8(&sB[brow][bc8], *reinterpret_cast<const u16x8*>(
                                    ebt + (size_t)(b * DOUTn + brow) * TKn + ks + bc8));
        }
        __syncthreads();
        half8 af = ld8h(&sA[rh * 16 + lr][kg8]);
#pragma unroll
        for (int n = 0; n < 4; n++) {
            half8 bf = ld8h(&sB[oq * 64 + n * 16 + lr][kg8]);
            acc[n] = __builtin_amdgcn_mfma_f32_16x16x32_f16(af, bf, acc[n], 0, 0, 0);
        }
    }
#pragma unroll
    for (int n = 0; n < 4; n++) {
        int col = oq * 64 + n * 16 + lr;
#pragma unroll
        for (int r = 0; r < 4; r++) {
            int rowL = rh * 16 + g * 4 + r;
            out[((size_t)(b * TQn + q0 + rowL)) * DOUTn + col] = acc[n][r];
        }
    }
}

// ---------------------------------------------------------------------------
extern "C" void kernel_launch(void* const* d_in, const int* in_sizes, int n_in,
                              void* d_out, int out_size, void* d_ws, size_t ws_size,
                              hipStream_t stream) {
    const float* dec = (const float*)d_in[0];
    const float* emb = (const float*)d_in[1];
    const int* emask = (const int*)d_in[2];
    const float* W = (const float*)d_in[3];
    const float* bias = (const float*)d_in[4];

    float* out = (float*)d_out;
    float* attn = out + (size_t)NROWS * DOUTn;

    char* wsb = (char*)d_ws;
    u16* ds_hi = (u16*)wsb;
    wsb += (size_t)NROWS * DOUTn * 2;
    u16* ds_lo = (u16*)wsb;
    wsb += (size_t)NROWS * DOUTn * 2;
    _Float16* embT = (_Float16*)wsb;
    wsb += (size_t)NB * DOUTn * TKn * 2;
    float* inv_sum = (float*)wsb;
    wsb += (size_t)NROWS * 4;
    float* partsum = (float*)wsb;  // 32 * 8192 fp32 = 1 MB

    k_embT<<<dim3(TKn / 64, DOUTn / 64, NB), 256, 0, stream>>>(emb, embT);
    k_linear<<<dim3(NROWS / 128, DOUTn / 64), 256, 0, stream>>>(dec, W, bias, ds_hi, ds_lo);
    k_scores_exp<<<dim3(TQn / 128, NKB, NB), 256, 0, stream>>>(ds_hi, ds_lo, emb, emask, attn, partsum);
    k_rowsum<<<dim3(NROWS / 256), 256, 0, stream>>>(partsum, inv_sum);
    k_pv3<<<dim3(TQn / 32, NB), 512, 0, stream>>>(attn, embT, inv_sum, out);
}